// Round 10
// baseline (418.491 us; speedup 1.0000x reference)
//
#include <hip/hip_runtime.h>
#include <hip/hip_bf16.h>

#define SLEN 512
#define BATCH 256
#define NIN 300
#define KP 320
#define NG 256
#define NH 64
#define BM 128
#define BN 128
#define BK 64
#define LDP 72   // padded LDS row length (bf16) -> 144B rows, 2-way (free) b128 reads

typedef float f32x4 __attribute__((ext_vector_type(4)));
typedef short s16x8 __attribute__((ext_vector_type(8)));
typedef short s16x4 __attribute__((ext_vector_type(4)));
typedef _Float16 f16x8 __attribute__((ext_vector_type(8)));
typedef _Float16 f16x2 __attribute__((ext_vector_type(2)));

__device__ __forceinline__ short f2bf(float f) {
  union { float f; unsigned u; } v; v.f = f;
  unsigned r = v.u + 0x7fffu + ((v.u >> 16) & 1u);  // RNE
  return (short)(r >> 16);
}

// Build WcatT[n][k] (bf16, K padded to 320), bcat[n], and Wg16[col][k] = f16(W_glt[k][col]).
__global__ void prep_w(const float* __restrict__ Wpt0, const float* __restrict__ bpt0,
                       const float* __restrict__ Wpt1, const float* __restrict__ bpt1,
                       const float* __restrict__ Wglt,
                       short* __restrict__ WcatT, float* __restrict__ bcat,
                       _Float16* __restrict__ Wg16) {
  int idx = blockIdx.x * 256 + threadIdx.x;
  if (idx < NG * KP) {
    int n = idx / KP, k = idx - n * KP;
    int g = n >> 6, h = n & 63;
    float w = 0.f;
    if (k < NIN) {
      if (h < 32) w = Wpt0[k * 128 + g * 32 + h];
      else        w = 0.5f * Wpt1[(k >> 1) * 128 + g * 32 + (h - 32)];
    }
    WcatT[idx] = f2bf(w);
  }
  if (idx < NG * NH) {  // transpose W_glt (64 x 256) -> Wg16 (256 x 64), f16
    int c = idx >> 6, k = idx & 63;
    Wg16[idx] = (_Float16)Wglt[k * NG + c];
  }
  if (idx < NG) {
    int g = idx >> 6, h = idx & 63;
    bcat[idx] = (h < 32) ? bpt0[g * 32 + h] : bpt1[g * 32 + h - 32];
  }
}

// C[row][n] = bf16(x[row]) @ WcatT^T + bcat   (row-chunk local)
__global__ __launch_bounds__(256) void gemm_i2h(
    const float* __restrict__ x, const short* __restrict__ WcatT,
    const float* __restrict__ bcat, float* __restrict__ C) {
  __shared__ short As[BM][LDP];
  __shared__ short Bs[BN][LDP];
  const int tid = threadIdx.x;
  const int m0 = blockIdx.x * BM;
  const int n0 = blockIdx.y * BN;
  const int lane = tid & 63;
  const int w = tid >> 6;
  const int wr = w >> 1, wc = w & 1;

  f32x4 acc[4][4];
#pragma unroll
  for (int m = 0; m < 4; ++m)
#pragma unroll
    for (int n = 0; n < 4; ++n) acc[m][n] = (f32x4){0.f, 0.f, 0.f, 0.f};

  const int arow_l = tid >> 4;        // 0..15
  const int acol   = (tid & 15) * 4;  // 0..60
  const int brow_l = tid >> 3;        // 0..31
  const int bcol   = (tid & 7) * 8;   // 0..56

  for (int k0 = 0; k0 < KP; k0 += BK) {
#pragma unroll
    for (int p = 0; p < 8; ++p) {
      int row = p * 16 + arow_l;
      int gk = k0 + acol;
      f32x4 v = (f32x4){0.f, 0.f, 0.f, 0.f};
      if (gk + 3 < NIN)  // 300 = 4*75 so vectors never straddle the boundary
        v = *reinterpret_cast<const f32x4*>(&x[(size_t)(m0 + row) * NIN + gk]);
      s16x4 sv;
      sv[0] = f2bf(v[0]); sv[1] = f2bf(v[1]); sv[2] = f2bf(v[2]); sv[3] = f2bf(v[3]);
      *reinterpret_cast<s16x4*>(&As[row][acol]) = sv;
    }
#pragma unroll
    for (int p = 0; p < 4; ++p) {
      int n = p * 32 + brow_l;
      s16x8 v = *reinterpret_cast<const s16x8*>(&WcatT[(size_t)(n0 + n) * KP + k0 + bcol]);
      *reinterpret_cast<s16x8*>(&Bs[n][bcol]) = v;
    }
    __syncthreads();
#pragma unroll
    for (int ks = 0; ks < 2; ++ks) {
      const int kk = ks * 32 + (lane >> 4) * 8;
      s16x8 a[4], b[4];
#pragma unroll
      for (int m = 0; m < 4; ++m)
        a[m] = *reinterpret_cast<const s16x8*>(&As[wr * 64 + m * 16 + (lane & 15)][kk]);
#pragma unroll
      for (int n = 0; n < 4; ++n)
        b[n] = *reinterpret_cast<const s16x8*>(&Bs[wc * 64 + n * 16 + (lane & 15)][kk]);
#pragma unroll
      for (int m = 0; m < 4; ++m)
#pragma unroll
        for (int n = 0; n < 4; ++n)
          acc[m][n] = __builtin_amdgcn_mfma_f32_16x16x32_bf16(a[m], b[n], acc[m][n], 0, 0, 0);
    }
    __syncthreads();
  }
  const int fc = lane & 15;
  const int fr = (lane >> 4) * 4;
#pragma unroll
  for (int n = 0; n < 4; ++n) {
    int col = n0 + wc * 64 + n * 16 + fc;
    float bias = bcat[col];
#pragma unroll
    for (int m = 0; m < 4; ++m) {
#pragma unroll
      for (int r = 0; r < 4; ++r) {
        int row = m0 + wr * 64 + m * 16 + fr + r;
        C[(size_t)row * NG + col] = acc[m][n][r] + bias;
      }
    }
  }
}

// TWO batch rows per block, interleaved in the SAME instruction stream (ILP
// hides the per-step latencies that TLP could not). 256 threads = 4 waves;
// wave ww, lane l: gate g = l>>4, hidden hidx = ww*16+(l&15), col = g*64+hidx.
// Each thread computes its gate column for BOTH rows; weights shared -> zero
// extra weight VGPRs. Round-8-proven pieces kept: LDS-alias weight residency,
// lgkm-only barrier, deep quad prefetch.
__global__ __launch_bounds__(256, 4)
void rec_seq(
    const float* __restrict__ i2h, const _Float16* __restrict__ Wg16,
    const float* __restrict__ h_in, const float* __restrict__ c_in,
    float* __restrict__ h_state, float* __restrict__ c_state,
    float* __restrict__ hs_out, float* __restrict__ hT_out, float* __restrict__ cT_out,
    int T, int is_last) {
  const int bA = blockIdx.x * 2;
  const int bB = bA + 1;
  const int tid = threadIdx.x;
  const int ww = tid >> 6;
  const int l = tid & 63;
  const int g = l >> 4;
  const int hidx = ww * 16 + (l & 15);
  const int col = g * 64 + hidx;

  // 32 KB LDS: stage weights [kk][col] (f16x8), then bytes [0..512) are
  // reused (ALIASED) as two double-buffered h vectors (2 rows x 2 x 64 f16).
  __shared__ __align__(16) char LB[8 * NG * 16];
  f16x8* Wst = reinterpret_cast<f16x8*>(LB);                    // Wst[kk*256+c]
  _Float16* hbufA = reinterpret_cast<_Float16*>(LB);            // [2][64]
  _Float16* hbufB = reinterpret_cast<_Float16*>(LB) + 2 * NH;   // [2][64]

  for (int e = tid; e < 8 * NG; e += 256) {
    int kk = e >> 8, c = e & 255;
    Wst[e] = *reinterpret_cast<const f16x8*>(Wg16 + (size_t)c * NH + kk * 8);
  }
  __syncthreads();

  f16x8 w0 = Wst[0 * NG + col], w1 = Wst[1 * NG + col];
  f16x8 w2 = Wst[2 * NG + col], w3 = Wst[3 * NG + col];
  f16x8 w4 = Wst[4 * NG + col], w5 = Wst[5 * NG + col];
  f16x8 w6 = Wst[6 * NG + col], w7 = Wst[7 * NG + col];

  float cAr = 0.f, cBr = 0.f, hAr = 0.f, hBr = 0.f;
  if (l < 16) {
    cAr = c_in[bA * NH + hidx];
    cBr = c_in[bB * NH + hidx];
  }
  float h0A = (tid < NH) ? h_in[bA * NH + tid] : 0.f;
  float h0B = (tid < NH) ? h_in[bB * NH + tid] : 0.f;
  __syncthreads();   // all weight reads complete before the overwrite below

  if (tid < NH) {
    hbufA[tid] = (_Float16)h0A;   // clobbers weight region -> regs must hold w
    hbufB[tid] = (_Float16)h0B;
  }
  __syncthreads();

  const size_t st = (size_t)NG * BATCH;   // i2h floats per step
  const float* ipA = i2h + (size_t)bA * NG + col;
  const float* ipB = ipA + NG;
  float* hpA = hs_out + (size_t)bA * NH + hidx;
  float* hpB = hpA + NH;
  const float mm = (g == 1) ? 2.f : 1.f;

#define PAIR(v, j) __builtin_shufflevector(v, v, 2*(j), 2*(j)+1)
#define D2(A, W, HV, J) A = __builtin_amdgcn_fdot2(PAIR(HV,J), PAIR(W,J), A, false);
#define CHUNK2(KK, W) { f16x8 hvA = hbA[KK]; f16x8 hvB = hbB[KK]; \
    D2(a0A, W, hvA, 0) D2(a0B, W, hvB, 0) D2(a1A, W, hvA, 1) D2(a1B, W, hvB, 1) \
    D2(a0A, W, hvA, 2) D2(a0B, W, hvB, 2) D2(a1A, W, hvA, 3) D2(a1B, W, hvB, 3) }

#define STEP2(CA, CB, PAR) { \
    const f16x8* hbA = reinterpret_cast<const f16x8*>(hbufA + (PAR) * NH); \
    const f16x8* hbB = reinterpret_cast<const f16x8*>(hbufB + (PAR) * NH); \
    float a0A = 0.f, a1A = 0.f, a0B = 0.f, a1B = 0.f; \
    CHUNK2(0, w0) CHUNK2(1, w1) CHUNK2(2, w2) CHUNK2(3, w3) \
    CHUNK2(4, w4) CHUNK2(5, w5) CHUNK2(6, w6) CHUNK2(7, w7) \
    float preA = (CA) + (a0A + a1A); \
    float preB = (CB) + (a0B + a1B); \
    float xxA = fminf(fmaxf(preA, -30.f), 30.f); \
    float xxB = fminf(fmaxf(preB, -30.f), 30.f); \
    float eA = __expf(-mm * xxA); \
    float eB = __expf(-mm * xxB); \
    float yA = 1.f / (1.f + eA); \
    float yB = 1.f / (1.f + eB); \
    float actA = (g == 1) ? (2.f * yA - 1.f) : yA; \
    float actB = (g == 1) ? (2.f * yB - 1.f) : yB; \
    float gA_ = __shfl(actA, l + 16); \
    float gB_ = __shfl(actB, l + 16); \
    float iA_ = __shfl(actA, l + 32); \
    float iB_ = __shfl(actB, l + 32); \
    float oA_ = __shfl(actA, l + 48); \
    float oB_ = __shfl(actB, l + 48); \
    if (l < 16) { \
      float c1A = actA * cAr + iA_ * gA_; cAr = c1A; \
      float c1B = actB * cBr + iB_ * gB_; cBr = c1B; \
      float ctA = fminf(fmaxf(c1A, -15.f), 15.f); \
      float ctB = fminf(fmaxf(c1B, -15.f), 15.f); \
      float e2A = __expf(-2.f * ctA); \
      float e2B = __expf(-2.f * ctB); \
      float thA = (1.f - e2A) / (1.f + e2A); \
      float thB = (1.f - e2B) / (1.f + e2B); \
      float h1A = oA_ * thA; hAr = h1A; \
      float h1B = oB_ * thB; hBr = h1B; \
      hbufA[(1 - (PAR)) * NH + hidx] = (_Float16)h1A; \
      hbufB[(1 - (PAR)) * NH + hidx] = (_Float16)h1B; \
      *hpA = h1A;  /* fire-and-forget */ \
      *hpB = h1B; \
    } \
    hpA += st >> 2; hpB += st >> 2; \
    asm volatile("s_waitcnt lgkmcnt(0)" ::: "memory"); \
    __builtin_amdgcn_s_barrier(); }

  int s = 0;
  if (T >= 8) {
    float c0A = ipA[0],      c1A = ipA[st],     c2A = ipA[2 * st], c3A = ipA[3 * st];
    float n0A = ipA[4 * st], n1A = ipA[5 * st], n2A = ipA[6 * st], n3A = ipA[7 * st];
    float c0B = ipB[0],      c1B = ipB[st],     c2B = ipB[2 * st], c3B = ipB[3 * st];
    float n0B = ipB[4 * st], n1B = ipB[5 * st], n2B = ipB[6 * st], n3B = ipB[7 * st];
    const float* ifA = ipA + 8 * st;
    const float* ifB = ipB + 8 * st;
    while (s + 4 <= T) {
      float f0A = 0.f, f1A = 0.f, f2A = 0.f, f3A = 0.f;
      float f0B = 0.f, f1B = 0.f, f2B = 0.f, f3B = 0.f;
      if (s + 8  < T) { f0A = ifA[0];      f0B = ifB[0]; }
      if (s + 9  < T) { f1A = ifA[st];     f1B = ifB[st]; }
      if (s + 10 < T) { f2A = ifA[2 * st]; f2B = ifB[2 * st]; }
      if (s + 11 < T) { f3A = ifA[3 * st]; f3B = ifB[3 * st]; }
      ifA += 4 * st; ifB += 4 * st;
      STEP2(c0A, c0B, 0)
      STEP2(c1A, c1B, 1)
      STEP2(c2A, c2B, 0)
      STEP2(c3A, c3B, 1)
      c0A = n0A; c1A = n1A; c2A = n2A; c3A = n3A;   // waits: loads 1 quad old
      c0B = n0B; c1B = n1B; c2B = n2B; c3B = n3B;
      n0A = f0A; n1A = f1A; n2A = f2A; n3A = f3A;   // waits: loads this quad top
      n0B = f0B; n1B = f1B; n2B = f2B; n3B = f3B;
      s += 4;
    }
    if (s < T) { STEP2(c0A, c0B, 0) s++; }
    if (s < T) { STEP2(c1A, c1B, 1) s++; }
    if (s < T) { STEP2(c2A, c2B, 0) s++; }
  } else {
    while (s < T) {
      float cvA = ipA[(size_t)s * st];
      float cvB = ipB[(size_t)s * st];
      if (s & 1) { STEP2(cvA, cvB, 1) }
      else       { STEP2(cvA, cvB, 0) }
      s++;
    }
  }

  if (l < 16) {
    h_state[bA * NH + hidx] = hAr;
    h_state[bB * NH + hidx] = hBr;
    c_state[bA * NH + hidx] = cAr;
    c_state[bB * NH + hidx] = cBr;
    if (is_last) {
      hT_out[bA * NH + hidx] = hAr;
      hT_out[bB * NH + hidx] = hBr;
      cT_out[bA * NH + hidx] = cAr;
      cT_out[bB * NH + hidx] = cBr;
    }
  }
}

// decoded[idx][j] = hs[idx][:] @ Wdec[:,j] + bdec[j], idx = s*BATCH+b
__global__ __launch_bounds__(256) void decode(
    const float* __restrict__ hs, const float* __restrict__ Wdec,
    const float* __restrict__ bdec, float* __restrict__ out, int n) {
  __shared__ float wl[NH * 3];
  __shared__ float bl[3];
  const int tid = threadIdx.x;
  if (tid < NH * 3) wl[tid] = Wdec[tid];
  if (tid < 3) bl[tid] = bdec[tid];
  __syncthreads();
  int idx = blockIdx.x * 256 + tid;
  if (idx >= n) return;
  const float* hp = hs + (size_t)idx * NH;
  float d0 = 0.f, d1 = 0.f, d2 = 0.f;
#pragma unroll
  for (int k = 0; k < NH; k += 4) {
    f32x4 h4 = *reinterpret_cast<const f32x4*>(&hp[k]);
#pragma unroll
    for (int j = 0; j < 4; ++j) {
      d0 += h4[j] * wl[(k + j) * 3 + 0];
      d1 += h4[j] * wl[(k + j) * 3 + 1];
      d2 += h4[j] * wl[(k + j) * 3 + 2];
    }
  }
  out[(size_t)idx * 3 + 0] = d0 + bl[0];
  out[(size_t)idx * 3 + 1] = d1 + bl[1];
  out[(size_t)idx * 3 + 2] = d2 + bl[2];
}

extern "C" void kernel_launch(void* const* d_in, const int* in_sizes, int n_in,
                              void* d_out, int out_size, void* d_ws, size_t ws_size,
                              hipStream_t stream) {
  const float* x    = (const float*)d_in[0];
  const float* h0   = (const float*)d_in[1];
  const float* c0   = (const float*)d_in[2];
  const float* Wpt0 = (const float*)d_in[3];
  const float* bpt0 = (const float*)d_in[4];
  const float* Wpt1 = (const float*)d_in[5];
  const float* bpt1 = (const float*)d_in[6];
  const float* Wglt = (const float*)d_in[7];
  const float* Wdec = (const float*)d_in[8];
  const float* bdec = (const float*)d_in[9];
  float* out = (float*)d_out;

  char* ws = (char*)d_ws;
  short*     WcatT   = (short*)(ws);              // 163840 B
  float*     bcat    = (float*)(ws + 163840);     // 1 KB
  _Float16*  Wg16    = (_Float16*)(ws + 164864);  // 32768 B (256 x 64 f16)
  float*     h_state = (float*)(ws + 197632);     // 64 KB
  float*     c_state = (float*)(ws + 263168);     // 64 KB
  const size_t base = 328704;

  // per-step chunk bytes: i2h (256*256*4) + hs (256*64*4)
  const size_t i2h_step = (size_t)BATCH * NG * 4;
  const size_t hs_step  = (size_t)BATCH * NH * 4;
  size_t avail = (ws_size > base) ? ws_size - base : 0;
  int T = (int)(avail / (i2h_step + hs_step));
  if (T > SLEN) T = SLEN;
  if (T < 1) T = 1;

  float* i2h = (float*)(ws + base);
  float* hs  = (float*)(ws + base + (size_t)T * i2h_step);

  prep_w<<<dim3((NG * KP + 255) / 256), dim3(256), 0, stream>>>(
      Wpt0, bpt0, Wpt1, bpt1, Wglt, WcatT, bcat, Wg16);

  for (int t0 = 0; t0 < SLEN; t0 += T) {
    int Tc = (SLEN - t0 < T) ? (SLEN - t0) : T;
    dim3 g(Tc * BATCH / BM, NG / BN);
    gemm_i2h<<<g, dim3(256), 0, stream>>>(
        x + (size_t)t0 * BATCH * NIN, WcatT, bcat, i2h);
    rec_seq<<<dim3(BATCH / 2), dim3(256), 0, stream>>>(
        i2h, Wg16,
        (t0 == 0) ? h0 : h_state, (t0 == 0) ? c0 : c_state,
        h_state, c_state, hs,
        out + (size_t)SLEN * BATCH * 3,
        out + (size_t)SLEN * BATCH * 3 + BATCH * NH,
        Tc, (t0 + Tc >= SLEN) ? 1 : 0);
    decode<<<dim3((Tc * BATCH + 255) / 256), dim3(256), 0, stream>>>(
        hs, Wdec, bdec, out + (size_t)t0 * BATCH * 3, Tc * BATCH);
  }
}